// Round 11
// baseline (171.817 us; speedup 1.0000x reference)
//
#include <hip/hip_runtime.h>
#include <hip/hip_bf16.h>

#define NN 100000      // nodes
#define FIN 256        // input features
#define FH 64          // hidden features
#define NEG 0.01f
#define NBUCK 256
#define BNODES ((NN + NBUCK - 1) / NBUCK)          // 391 nodes per coarse bucket
#define P1_CH 4096
#define WP 264         // LDS pitch for W^T (bf16 elems): 2-way bank conflict only
#define SRCMASK 0x1FFFF   // 17 bits (NN < 131072)
#define SLAB 16384     // slab capacity per coarse bucket (mean fill ~6250)
#define GBA 196        // gemm blocks (256 rows each) in fusedA
#define GBB 195        // gemm blocks in fusedB  (196+195 = 391 = ceil(NN/256))

typedef __attribute__((ext_vector_type(8))) short short8x;
typedef __attribute__((ext_vector_type(4))) float f32x4;

__device__ inline unsigned short f2bf_hw(float f) {
    __hip_bfloat16 h = __float2bfloat16(f);
    return __builtin_bit_cast(unsigned short, h);
}
__device__ inline float bf2f(unsigned short s) {
    return __uint_as_float(((unsigned)s) << 16);
}

__device__ inline long long load_idx(const void* p, long long i, int is64) {
    if (is64) return ((const long long*)p)[i];
    return (long long)((const int*)p)[i];
}

// wave-ballot int64 detection: hi-words of first 64 entries all zero => int64
__device__ inline int is64_ballot(const void* p) {
    const int* p32 = (const int*)p;
    int lane = threadIdx.x & 63;
    int ok = (p32[2 * lane + 1] == 0) ? 1 : 0;
    unsigned long long m = __ballot(ok);
    return m == ~0ULL ? 1 : 0;
}

// ---------------------------------------------------------------------------
// ws layout (CSR path), bytes:
//   hbf[NN*FH] bf16 | ne[NN*FH] f32 (pairs slab int[NBUCK*SLAB] staged here) |
//   dinv[NN] | cursor[NN+1] | bucket[E] | coarse_cursor[NBUCK]
// Fallback (ws too small): h f32 | ne f32 | deg | flag  (round-1 scatter)
// ---------------------------------------------------------------------------

__global__ void zero_slab_kernel(int* __restrict__ coarse_cursor) {
    coarse_cursor[threadIdx.x] = threadIdx.x * SLAB;
}

// ---------------- gemm role: 256 rows of hbf = bf16(x @ W_conv) -------------
// W staged once per block, 4 row-tiles of 64 rows computed per block.
__device__ void gemm_role(const float* __restrict__ x, const float* __restrict__ W,
                          unsigned short* __restrict__ hbf, int gb, char* smem) {
    unsigned short* Wt = (unsigned short*)smem;   // [col][k], pitch WP

    for (int i = threadIdx.x; i < FIN * FH; i += 256) {
        int k = i >> 6, c = i & 63;
        Wt[c * WP + k] = f2bf_hw(W[i]);
    }
    __syncthreads();

    const int wv = threadIdx.x >> 6;
    const int lane = threadIdx.x & 63;
    const int c = lane & 15;
    const int eg = lane >> 4;

#pragma unroll
    for (int t4 = 0; t4 < 4; ++t4) {
        const int row0 = gb * 256 + t4 * 64 + wv * 16;
        int rowA = row0 + c;
        if (rowA >= NN) rowA = NN - 1;
        const float* aptr = x + (long long)rowA * FIN;

        f32x4 acc[4] = {{0,0,0,0},{0,0,0,0},{0,0,0,0},{0,0,0,0}};

#pragma unroll
        for (int kk = 0; kk < 8; ++kk) {
            const int kbase = kk * 32 + eg * 8;
            float4 f0 = *(const float4*)(aptr + kbase);
            float4 f1 = *(const float4*)(aptr + kbase + 4);
            short8x a;
            a[0] = (short)f2bf_hw(f0.x); a[1] = (short)f2bf_hw(f0.y);
            a[2] = (short)f2bf_hw(f0.z); a[3] = (short)f2bf_hw(f0.w);
            a[4] = (short)f2bf_hw(f1.x); a[5] = (short)f2bf_hw(f1.y);
            a[6] = (short)f2bf_hw(f1.z); a[7] = (short)f2bf_hw(f1.w);
#pragma unroll
            for (int cb = 0; cb < 4; ++cb) {
                short8x b = *(const short8x*)(&Wt[(cb * 16 + c) * WP + kbase]);
                acc[cb] = __builtin_amdgcn_mfma_f32_16x16x32_bf16(a, b, acc[cb], 0, 0, 0);
            }
        }

#pragma unroll
        for (int cb = 0; cb < 4; ++cb) {
#pragma unroll
            for (int r = 0; r < 4; ++r) {
                int rowO = row0 + eg * 4 + r;
                if (rowO < NN)
                    hbf[(long long)rowO * FH + cb * 16 + c] = f2bf_hw(acc[cb][r]);
            }
        }
    }
}

// ---------------- part role: direct slab partition (no precount) ------------
__device__ void part_role(const void* __restrict__ ei, int* __restrict__ coarse_cursor,
                          int* __restrict__ pairs, int E, int pb, char* smem) {
    int* hist = (int*)smem;
    int* blkoff = hist + NBUCK;
    const int t = threadIdx.x;
    hist[t] = 0;
    __syncthreads();
    const int is64 = is64_ballot(ei);
    const long long base = (long long)pb * P1_CH;

    int pkv[16], bkt[16], rnk[16];
#pragma unroll
    for (int i = 0; i < 16; ++i) {
        long long e = base + i * 256 + t;
        if (e < E) {
            int s = (int)load_idx(ei, e, is64);
            int d = (int)load_idx(ei, (long long)E + e, is64);
            int b = (int)((unsigned)d / BNODES);
            int dl = d - b * BNODES;
            pkv[i] = s | (dl << 17);
            bkt[i] = b;
            rnk[i] = atomicAdd(&hist[b], 1);
        } else {
            bkt[i] = -1;
        }
    }
    __syncthreads();
    blkoff[t] = atomicAdd(&coarse_cursor[t], hist[t]);
    __syncthreads();
#pragma unroll
    for (int i = 0; i < 16; ++i) {
        if (bkt[i] >= 0) {
            int pos = blkoff[bkt[i]] + rnk[i];
            if (pos < (bkt[i] + 1) * SLAB)   // overflow clamp (never hit: uniform dst)
                pairs[pos] = pkv[i];
        }
    }
}

// ---------------- place role: in-block bucket-prefix + degree scan ----------
__device__ void place_role(const int* __restrict__ pairs,
                           const int* __restrict__ coarse_cursor,
                           int* __restrict__ cursor, float* __restrict__ dinv,
                           int* __restrict__ bucket, int b, char* smem) {
    int* cnt = (int*)smem;               // BNODES
    int* nstart = cnt + BNODES;          // BNODES+1
    int* wsum = nstart + BNODES + 1;     // 8 (padded)
    int* sh = wsum + 8;                  // 2: lo, cntb
    const int t = threadIdx.x;
    const int lane = t & 63, w = t >> 6;

    // per-bucket counts from slab cursors; block-wide exclusive scan
    int myc = coarse_cursor[t] - t * SLAB;
    if (myc > SLAB) myc = SLAB;
    int incl0 = myc;
#pragma unroll
    for (int m = 1; m < 64; m <<= 1) {
        int u = __shfl_up(incl0, m, 64);
        if (lane >= m) incl0 += u;
    }
    if (lane == 63) wsum[w] = incl0;
    __syncthreads();
    int woff0 = 0;
    for (int i = 0; i < w; ++i) woff0 += wsum[i];
    int ex0 = woff0 + incl0 - myc;
    if (t == b) { sh[0] = ex0; sh[1] = myc; }
    __syncthreads();
    const int lo = sh[0];
    const int cntb = sh[1];
    const int g0 = b * BNODES;
    const int nb = (NN - g0 < BNODES) ? (NN - g0) : BNODES;
    const int sb = b * SLAB;

    for (int j = t; j < nb; j += 256) cnt[j] = 0;
    __syncthreads();

    // pass 1: local degree count
    for (int i = t; i < cntb; i += 256)
        atomicAdd(&cnt[pairs[sb + i] >> 17], 1);
    __syncthreads();

    // exclusive scan of cnt[0..nb) -> nstart[0..nb]
    const int i0 = 2 * t, i1 = 2 * t + 1;
    const int v0 = (i0 < nb) ? cnt[i0] : 0;
    const int v1 = (i1 < nb) ? cnt[i1] : 0;
    const int s = v0 + v1;
    int incl = s;
#pragma unroll
    for (int m = 1; m < 64; m <<= 1) {
        int u = __shfl_up(incl, m, 64);
        if (lane >= m) incl += u;
    }
    __syncthreads();           // protect wsum reuse
    if (lane == 63) wsum[w] = incl;
    __syncthreads();
    int woff = 0;
    for (int i = 0; i < w; ++i) woff += wsum[i];
    const int ex = woff + incl - s;
    if (i0 <= nb) nstart[i0] = ex;
    if (i1 <= nb) nstart[i1] = ex + v0;
    __syncthreads();

    // emit cursor + dinv (coalesced)
    for (int j = t; j <= nb; j += 256) {
        int g = g0 + j;
        if (g <= NN) cursor[g] = lo + nstart[j];
    }
    for (int j = t; j < nb; j += 256)
        dinv[g0 + j] = rsqrtf(1.0f + (float)(nstart[j + 1] - nstart[j]));

    // pass 2: place
    for (int j = t; j < nb; j += 256) cnt[j] = 0;
    __syncthreads();
    for (int i = t; i < cntb; i += 256) {
        int p = pairs[sb + i];
        int local = p >> 17;
        int r = atomicAdd(&cnt[local], 1);
        bucket[lo + nstart[local] + r] = p & SRCMASK;
    }
}

// ---------------- fused kernels (block-range dispatch) ----------------------
__global__ __launch_bounds__(256) void fusedA_kernel(const float* __restrict__ x,
                                                     const float* __restrict__ W,
                                                     unsigned short* __restrict__ hbf,
                                                     const void* __restrict__ ei,
                                                     int* __restrict__ coarse_cursor,
                                                     int* __restrict__ pairs, int E) {
    __shared__ __align__(16) char smem[FH * WP * 2];
    const int b = blockIdx.x;
    if (b < GBA) gemm_role(x, W, hbf, b, smem);
    else         part_role(ei, coarse_cursor, pairs, E, b - GBA, smem);
}

__global__ __launch_bounds__(256) void fusedB_kernel(const float* __restrict__ x,
                                                     const float* __restrict__ W,
                                                     unsigned short* __restrict__ hbf,
                                                     const int* __restrict__ pairs,
                                                     const int* __restrict__ coarse_cursor,
                                                     int* __restrict__ cursor,
                                                     float* __restrict__ dinv,
                                                     int* __restrict__ bucket) {
    __shared__ __align__(16) char smem[FH * WP * 2];
    const int b = blockIdx.x;
    if (b < GBB) gemm_role(x, W, hbf, GBA + b, smem);
    else         place_role(pairs, coarse_cursor, cursor, dinv, bucket, b - GBB, smem);
}

// one wave per node, 8 edges in flight (proven R6/R9 form)
__global__ __launch_bounds__(256) void gather8_kernel(const unsigned short* __restrict__ hbf,
                                                      const float* __restrict__ dinv,
                                                      const int* __restrict__ cursor,
                                                      const int* __restrict__ bucket,
                                                      const float* __restrict__ b_conv,
                                                      float* __restrict__ ne) {
    const int node = blockIdx.x * 4 + (threadIdx.x >> 6);
    if (node >= NN) return;
    const int lane = threadIdx.x & 63;
    const int sub = lane & 7;
    const int eg = lane >> 3;

    const int base = cursor[node];
    const int end  = cursor[node + 1];
    const float dd = dinv[node];

    float acc[8] = {0,0,0,0,0,0,0,0};
    for (int k = base + eg; k < end; k += 8) {
        int s = bucket[k];
        float nrm = dinv[s] * dd;
        short8x hv = *(const short8x*)(hbf + (long long)s * FH + sub * 8);
#pragma unroll
        for (int j = 0; j < 8; ++j)
            acc[j] += bf2f((unsigned short)hv[j]) * nrm;
    }
#pragma unroll
    for (int m = 8; m < 64; m <<= 1) {
#pragma unroll
        for (int j = 0; j < 8; ++j) acc[j] += __shfl_xor(acc[j], m);
    }
    if (eg == 0) {
        short8x hs = *(const short8x*)(hbf + (long long)node * FH + sub * 8);
        float r[8];
#pragma unroll
        for (int j = 0; j < 8; ++j) {
            float v = acc[j] + bf2f((unsigned short)hs[j]) * dd * dd + b_conv[sub * 8 + j];
            r[j] = v >= 0.f ? v : NEG * v;
        }
        float4* o = (float4*)(ne + (long long)node * FH + sub * 8);
        o[0] = make_float4(r[0], r[1], r[2], r[3]);
        o[1] = make_float4(r[4], r[5], r[6], r[7]);
    }
}

// ------------------------- MLP head -----------------------------------------
__global__ __launch_bounds__(256) void mlp_kernel(const float* __restrict__ ne,
                                                  const void* __restrict__ idx,
                                                  const float* __restrict__ W1,
                                                  const float* __restrict__ b1,
                                                  const float* __restrict__ W2,
                                                  const float* __restrict__ b2,
                                                  float* __restrict__ out,
                                                  int B) {
    const int lane = threadIdx.x & 63;
    const int wid = threadIdx.x >> 6;
    const int is64 = is64_ballot(idx);

    float w1a[16], w1b[16], b1r[16], w2r[16];
#pragma unroll
    for (int o = 0; o < 16; ++o) {
        w1a[o] = W1[lane * 16 + o];
        w1b[o] = W1[(64 + lane) * 16 + o];
        b1r[o] = b1[o];
        w2r[o] = W2[o];
    }
    const float b2v = b2[0];

    for (int pair = blockIdx.x * 4 + wid; pair < B; pair += gridDim.x * 4) {
        long long i0 = load_idx(idx, 2LL * pair, is64);
        long long i1 = load_idx(idx, 2LL * pair + 1, is64);
        float a = ne[i0 * FH + lane];
        float b = ne[i1 * FH + lane];

        float acc[16];
#pragma unroll
        for (int o = 0; o < 16; ++o) acc[o] = a * w1a[o] + b * w1b[o];
#pragma unroll
        for (int m = 1; m < 64; m <<= 1) {
#pragma unroll
            for (int o = 0; o < 16; ++o) acc[o] += __shfl_xor(acc[o], m, 64);
        }
        if (lane == 0) {
            float s = b2v;
#pragma unroll
            for (int o = 0; o < 16; ++o) {
                float z = acc[o] + b1r[o];
                z = z >= 0.f ? z : NEG * z;
                s += z * w2r[o];
            }
            out[pair] = 1.f / (1.f + expf(-s));
        }
    }
}

// ------------------------- fallback (round-1) path --------------------------

__global__ void detect_kernel(const int* __restrict__ ei32, int* __restrict__ flag) {
    if (blockIdx.x == 0 && threadIdx.x == 0) {
        int ok = 1;
        for (int k = 0; k < 64; ++k)
            if (ei32[2 * k + 1] != 0) { ok = 0; break; }
        *flag = ok;
    }
}

__global__ __launch_bounds__(256) void gemm_kernel(const float* __restrict__ x,
                                                   const float* __restrict__ W,
                                                   float* __restrict__ h) {
    __shared__ float xs[4 * FIN];
    __shared__ float part[4][4][FH];

    const int col = threadIdx.x & 63;
    const int kseg = threadIdx.x >> 6;

    float wreg[64];
#pragma unroll
    for (int kk = 0; kk < 64; ++kk)
        wreg[kk] = W[(kseg * 64 + kk) * FH + col];

    for (int row0 = blockIdx.x * 4; row0 < NN; row0 += gridDim.x * 4) {
        const float4* xv = (const float4*)(x + (long long)row0 * FIN);
        ((float4*)xs)[threadIdx.x] = xv[threadIdx.x];
        __syncthreads();

        float acc[4] = {0.f, 0.f, 0.f, 0.f};
#pragma unroll
        for (int kk = 0; kk < 64; ++kk) {
            const float w = wreg[kk];
            const int k = kseg * 64 + kk;
#pragma unroll
            for (int r = 0; r < 4; ++r)
                acc[r] += xs[r * FIN + k] * w;
        }
#pragma unroll
        for (int r = 0; r < 4; ++r) part[r][kseg][col] = acc[r];
        __syncthreads();

        const int row = threadIdx.x >> 6;
        float s = part[row][0][col] + part[row][1][col] + part[row][2][col] + part[row][3][col];
        h[(long long)(row0 + row) * FH + col] = s;
        __syncthreads();
    }
}

__global__ __launch_bounds__(256) void init_kernel(float* __restrict__ ne,
                                                   float* __restrict__ deg,
                                                   const float* __restrict__ b_conv) {
    int idx = blockIdx.x * 256 + threadIdx.x;
    if (idx < NN * FH) ne[idx] = b_conv[idx & (FH - 1)];
    if (idx < NN) deg[idx] = 1.0f;
}

__global__ __launch_bounds__(256) void deg_kernel(const void* __restrict__ ei,
                                                  float* __restrict__ deg,
                                                  int E, const int* __restrict__ flag) {
    int e = blockIdx.x * 256 + threadIdx.x;
    if (e >= E) return;
    long long d = load_idx(ei, (long long)E + e, *flag);
    atomicAdd(&deg[d], 1.0f);
}

__global__ __launch_bounds__(256) void rsqrt_kernel(float* __restrict__ deg) {
    int i = blockIdx.x * 256 + threadIdx.x;
    if (i < NN) deg[i] = rsqrtf(deg[i]);
}

__global__ __launch_bounds__(256) void selfloop_kernel(const float* __restrict__ h,
                                                       const float* __restrict__ dinv,
                                                       float* __restrict__ ne) {
    int idx = blockIdx.x * 256 + threadIdx.x;
    if (idx >= NN * FH) return;
    int i = idx >> 6;
    float di = dinv[i];
    ne[idx] += h[idx] * di * di;
}

__global__ __launch_bounds__(256) void edge_agg_kernel(const void* __restrict__ ei,
                                                       const float* __restrict__ dinv,
                                                       const float* __restrict__ h,
                                                       float* __restrict__ ne,
                                                       int E, const int* __restrict__ flag) {
    long long t = (long long)blockIdx.x * 256 + threadIdx.x;
    long long e = t >> 4;
    int sub = (int)(t & 15);
    if (e >= E) return;
    int is64 = *flag;
    long long s = load_idx(ei, e, is64);
    long long d = load_idx(ei, (long long)E + e, is64);
    float nrm = dinv[s] * dinv[d];
    float4 hv = *(const float4*)(h + s * FH + sub * 4);
    float* np_ = ne + d * FH + sub * 4;
    atomicAdd(np_ + 0, hv.x * nrm);
    atomicAdd(np_ + 1, hv.y * nrm);
    atomicAdd(np_ + 2, hv.z * nrm);
    atomicAdd(np_ + 3, hv.w * nrm);
}

__global__ __launch_bounds__(256) void mlp_fb_kernel(const float* __restrict__ ne,
                                                     const void* __restrict__ idx,
                                                     const float* __restrict__ W1,
                                                     const float* __restrict__ b1,
                                                     const float* __restrict__ W2,
                                                     const float* __restrict__ b2,
                                                     float* __restrict__ out,
                                                     int B, const int* __restrict__ flag) {
    const int lane = threadIdx.x & 63;
    const int wid = threadIdx.x >> 6;

    float w1a[16], w1b[16], b1r[16], w2r[16];
#pragma unroll
    for (int o = 0; o < 16; ++o) {
        w1a[o] = W1[lane * 16 + o];
        w1b[o] = W1[(64 + lane) * 16 + o];
        b1r[o] = b1[o];
        w2r[o] = W2[o];
    }
    const float b2v = b2[0];
    const int is64 = *flag;

    for (int pair = blockIdx.x * 4 + wid; pair < B; pair += gridDim.x * 4) {
        long long i0 = load_idx(idx, 2LL * pair, is64);
        long long i1 = load_idx(idx, 2LL * pair + 1, is64);
        float a = ne[i0 * FH + lane];
        float b = ne[i1 * FH + lane];
        a = a >= 0.f ? a : NEG * a;
        b = b >= 0.f ? b : NEG * b;

        float acc[16];
#pragma unroll
        for (int o = 0; o < 16; ++o) acc[o] = a * w1a[o] + b * w1b[o];
#pragma unroll
        for (int m = 1; m < 64; m <<= 1) {
#pragma unroll
            for (int o = 0; o < 16; ++o) acc[o] += __shfl_xor(acc[o], m, 64);
        }
        if (lane == 0) {
            float s = b2v;
#pragma unroll
            for (int o = 0; o < 16; ++o) {
                float z = acc[o] + b1r[o];
                z = z >= 0.f ? z : NEG * z;
                s += z * w2r[o];
            }
            out[pair] = 1.f / (1.f + expf(-s));
        }
    }
}

extern "C" void kernel_launch(void* const* d_in, const int* in_sizes, int n_in,
                              void* d_out, int out_size, void* d_ws, size_t ws_size,
                              hipStream_t stream) {
    const float* x      = (const float*)d_in[0];
    const void*  ei     = d_in[1];
    const void*  index  = d_in[2];
    const float* W_conv = (const float*)d_in[3];
    const float* b_conv = (const float*)d_in[4];
    const float* W1     = (const float*)d_in[5];
    const float* b1     = (const float*)d_in[6];
    const float* W2     = (const float*)d_in[7];
    const float* b2     = (const float*)d_in[8];
    float* out = (float*)d_out;

    const int E = in_sizes[1] / 2;   // 1.6M
    const int B = in_sizes[2] / 2;   // 16384

    const size_t need_new = (size_t)NN * FH * 2
                          + ((size_t)NN * FH + NN + (NN + 1) + (size_t)E + NBUCK) * 4;

    if (ws_size >= need_new && (size_t)NBUCK * SLAB <= (size_t)NN * FH) {
        unsigned short* hbf = (unsigned short*)d_ws;
        float* ne       = (float*)(hbf + (long long)NN * FH);
        float* dinv     = ne + (long long)NN * FH;
        int*   cursor   = (int*)(dinv + NN);          // NN+1 entries
        int*   bucket   = cursor + (NN + 1);
        int*   coarse_cursor = bucket + E;            // NBUCK
        int*   pairs    = (int*)ne;                   // slab array in dead ne buffer

        const int npart = (E + P1_CH - 1) / P1_CH;

        zero_slab_kernel<<<1, 256, 0, stream>>>(coarse_cursor);
        fusedA_kernel<<<GBA + npart, 256, 0, stream>>>(x, W_conv, hbf, ei, coarse_cursor, pairs, E);
        fusedB_kernel<<<GBB + NBUCK, 256, 0, stream>>>(x, W_conv, hbf, pairs, coarse_cursor, cursor, dinv, bucket);
        gather8_kernel<<<(NN + 3) / 4, 256, 0, stream>>>(hbf, dinv, cursor, bucket, b_conv, ne);
        mlp_kernel<<<512, 256, 0, stream>>>(ne, index, W1, b1, W2, b2, out, B);
    } else {
        // fallback: round-1 atomic scatter (fp32)
        float* h   = (float*)d_ws;
        float* ne  = h + (long long)NN * FH;
        float* deg = ne + (long long)NN * FH;
        int* flag  = (int*)(deg + NN);

        detect_kernel<<<1, 64, 0, stream>>>((const int*)ei, flag);
        init_kernel<<<(NN * FH + 255) / 256, 256, 0, stream>>>(ne, deg, b_conv);
        gemm_kernel<<<2048, 256, 0, stream>>>(x, W_conv, h);
        deg_kernel<<<(E + 255) / 256, 256, 0, stream>>>(ei, deg, E, flag);
        rsqrt_kernel<<<(NN + 255) / 256, 256, 0, stream>>>(deg);
        selfloop_kernel<<<(NN * FH + 255) / 256, 256, 0, stream>>>(h, deg, ne);
        edge_agg_kernel<<<(int)(((long long)E * 16 + 255) / 256), 256, 0, stream>>>(ei, deg, h, ne, E, flag);
        mlp_fb_kernel<<<512, 256, 0, stream>>>(ne, index, W1, b1, W2, b2, out, B, flag);
    }
}

// Round 12
// 150.634 us; speedup vs baseline: 1.1406x; 1.1406x over previous
//
#include <hip/hip_runtime.h>
#include <hip/hip_bf16.h>

#define NN 100000      // nodes
#define FIN 256        // input features
#define FH 64          // hidden features
#define NEG 0.01f
#define NBUCK 256
#define BNODES ((NN + NBUCK - 1) / NBUCK)          // 391 nodes per coarse bucket
#define P1_CH 4096
#define WP 264         // LDS pitch for W^T (bf16 elems)
#define SRCMASK 0x1FFFF   // 17 bits (NN < 131072)
#define SLAB 16384     // slab capacity per coarse bucket (mean fill ~6250)
#define GA 782         // gemm blocks (64 rows each) in fusedA
#define GB 781         // gemm blocks in fusedB  (782+781 = 1563 = ceil(NN/64))

typedef __attribute__((ext_vector_type(8))) short short8x;
typedef __attribute__((ext_vector_type(4))) float f32x4;

__device__ inline unsigned short f2bf_hw(float f) {
    __hip_bfloat16 h = __float2bfloat16(f);
    return __builtin_bit_cast(unsigned short, h);
}
__device__ inline float bf2f(unsigned short s) {
    return __uint_as_float(((unsigned)s) << 16);
}

__device__ inline long long load_idx(const void* p, long long i, int is64) {
    if (is64) return ((const long long*)p)[i];
    return (long long)((const int*)p)[i];
}

// wave-ballot int64 detection: hi-words of first 64 entries all zero => int64
__device__ inline int is64_ballot(const void* p) {
    const int* p32 = (const int*)p;
    int lane = threadIdx.x & 63;
    int ok = (p32[2 * lane + 1] == 0) ? 1 : 0;
    unsigned long long m = __ballot(ok);
    return m == ~0ULL ? 1 : 0;
}

// ---------------------------------------------------------------------------
// ws layout (CSR path), bytes:
//   hbf[NN*FH] bf16 | ne[NN*FH] f32 (pairs slab int[NBUCK*SLAB] staged here) |
//   dinv[NN] | cursor[NN+1] | bucket[E] | coarse_cursor[NBUCK]
// Fallback (ws too small): h f32 | ne f32 | deg | flag  (round-1 scatter)
// ---------------------------------------------------------------------------

__global__ void zero_slab_kernel(int* __restrict__ coarse_cursor) {
    coarse_cursor[threadIdx.x] = threadIdx.x * SLAB;
}

// ---------------- gemm role: 64 rows of hbf = bf16(x @ W_conv) --------------
// (R10-proven granularity: one 64-row tile per block)
__device__ void gemm_role(const float* __restrict__ x, const float* __restrict__ W,
                          unsigned short* __restrict__ hbf, int gb, char* smem) {
    unsigned short* Wt = (unsigned short*)smem;   // [col][k], pitch WP

    for (int i = threadIdx.x; i < FIN * FH; i += 256) {
        int k = i >> 6, c = i & 63;
        Wt[c * WP + k] = f2bf_hw(W[i]);
    }
    __syncthreads();

    const int wv = threadIdx.x >> 6;
    const int lane = threadIdx.x & 63;
    const int c = lane & 15;
    const int eg = lane >> 4;

    const int row0 = (gb * 4 + wv) * 16;
    int rowA = row0 + c;
    if (rowA >= NN) rowA = NN - 1;
    const float* aptr = x + (long long)rowA * FIN;

    f32x4 acc[4] = {{0,0,0,0},{0,0,0,0},{0,0,0,0},{0,0,0,0}};

#pragma unroll
    for (int kk = 0; kk < 8; ++kk) {
        const int kbase = kk * 32 + eg * 8;
        float4 f0 = *(const float4*)(aptr + kbase);
        float4 f1 = *(const float4*)(aptr + kbase + 4);
        short8x a;
        a[0] = (short)f2bf_hw(f0.x); a[1] = (short)f2bf_hw(f0.y);
        a[2] = (short)f2bf_hw(f0.z); a[3] = (short)f2bf_hw(f0.w);
        a[4] = (short)f2bf_hw(f1.x); a[5] = (short)f2bf_hw(f1.y);
        a[6] = (short)f2bf_hw(f1.z); a[7] = (short)f2bf_hw(f1.w);
#pragma unroll
        for (int cb = 0; cb < 4; ++cb) {
            short8x b = *(const short8x*)(&Wt[(cb * 16 + c) * WP + kbase]);
            acc[cb] = __builtin_amdgcn_mfma_f32_16x16x32_bf16(a, b, acc[cb], 0, 0, 0);
        }
    }

#pragma unroll
    for (int cb = 0; cb < 4; ++cb) {
#pragma unroll
        for (int r = 0; r < 4; ++r) {
            int rowO = row0 + eg * 4 + r;
            if (rowO < NN)
                hbf[(long long)rowO * FH + cb * 16 + c] = f2bf_hw(acc[cb][r]);
        }
    }
}

// ---------------- part role: direct slab partition (no precount) ------------
__device__ void part_role(const void* __restrict__ ei, int* __restrict__ coarse_cursor,
                          int* __restrict__ pairs, int E, int pb, char* smem) {
    int* hist = (int*)smem;
    int* blkoff = hist + NBUCK;
    const int t = threadIdx.x;
    hist[t] = 0;
    __syncthreads();
    const int is64 = is64_ballot(ei);
    const long long base = (long long)pb * P1_CH;

    int pkv[16], bkt[16], rnk[16];
#pragma unroll
    for (int i = 0; i < 16; ++i) {
        long long e = base + i * 256 + t;
        if (e < E) {
            int s = (int)load_idx(ei, e, is64);
            int d = (int)load_idx(ei, (long long)E + e, is64);
            int b = (int)((unsigned)d / BNODES);
            int dl = d - b * BNODES;
            pkv[i] = s | (dl << 17);
            bkt[i] = b;
            rnk[i] = atomicAdd(&hist[b], 1);
        } else {
            bkt[i] = -1;
        }
    }
    __syncthreads();
    blkoff[t] = atomicAdd(&coarse_cursor[t], hist[t]);
    __syncthreads();
#pragma unroll
    for (int i = 0; i < 16; ++i) {
        if (bkt[i] >= 0) {
            int pos = blkoff[bkt[i]] + rnk[i];
            if (pos < (bkt[i] + 1) * SLAB)   // overflow clamp (never hit: uniform dst)
                pairs[pos] = pkv[i];
        }
    }
}

// ---------------- place role: in-block bucket-prefix + degree scan ----------
// (R11-verified logic)
__device__ void place_role(const int* __restrict__ pairs,
                           const int* __restrict__ coarse_cursor,
                           int* __restrict__ cursor, float* __restrict__ dinv,
                           int* __restrict__ bucket, int b, char* smem) {
    int* cnt = (int*)smem;               // BNODES
    int* nstart = cnt + BNODES;          // BNODES+1
    int* wsum = nstart + BNODES + 1;     // 8 (padded)
    int* sh = wsum + 8;                  // 2: lo, cntb
    const int t = threadIdx.x;
    const int lane = t & 63, w = t >> 6;

    // per-bucket counts from slab cursors; block-wide exclusive scan
    int myc = coarse_cursor[t] - t * SLAB;
    if (myc > SLAB) myc = SLAB;
    int incl0 = myc;
#pragma unroll
    for (int m = 1; m < 64; m <<= 1) {
        int u = __shfl_up(incl0, m, 64);
        if (lane >= m) incl0 += u;
    }
    if (lane == 63) wsum[w] = incl0;
    __syncthreads();
    int woff0 = 0;
    for (int i = 0; i < w; ++i) woff0 += wsum[i];
    int ex0 = woff0 + incl0 - myc;
    if (t == b) { sh[0] = ex0; sh[1] = myc; }
    __syncthreads();
    const int lo = sh[0];
    const int cntb = sh[1];
    const int g0 = b * BNODES;
    const int nb = (NN - g0 < BNODES) ? (NN - g0) : BNODES;
    const int sb = b * SLAB;

    for (int j = t; j < nb; j += 256) cnt[j] = 0;
    __syncthreads();

    // pass 1: local degree count
    for (int i = t; i < cntb; i += 256)
        atomicAdd(&cnt[pairs[sb + i] >> 17], 1);
    __syncthreads();

    // exclusive scan of cnt[0..nb) -> nstart[0..nb]
    const int i0 = 2 * t, i1 = 2 * t + 1;
    const int v0 = (i0 < nb) ? cnt[i0] : 0;
    const int v1 = (i1 < nb) ? cnt[i1] : 0;
    const int s = v0 + v1;
    int incl = s;
#pragma unroll
    for (int m = 1; m < 64; m <<= 1) {
        int u = __shfl_up(incl, m, 64);
        if (lane >= m) incl += u;
    }
    __syncthreads();           // protect wsum reuse
    if (lane == 63) wsum[w] = incl;
    __syncthreads();
    int woff = 0;
    for (int i = 0; i < w; ++i) woff += wsum[i];
    const int ex = woff + incl - s;
    if (i0 <= nb) nstart[i0] = ex;
    if (i1 <= nb) nstart[i1] = ex + v0;
    __syncthreads();

    // emit cursor + dinv (coalesced)
    for (int j = t; j <= nb; j += 256) {
        int g = g0 + j;
        if (g <= NN) cursor[g] = lo + nstart[j];
    }
    for (int j = t; j < nb; j += 256)
        dinv[g0 + j] = rsqrtf(1.0f + (float)(nstart[j + 1] - nstart[j]));

    // pass 2: place
    for (int j = t; j < nb; j += 256) cnt[j] = 0;
    __syncthreads();
    for (int i = t; i < cntb; i += 256) {
        int p = pairs[sb + i];
        int local = p >> 17;
        int r = atomicAdd(&cnt[local], 1);
        bucket[lo + nstart[local] + r] = p & SRCMASK;
    }
}

// ---------------- fused kernels (block-range dispatch) ----------------------
__global__ __launch_bounds__(256) void fusedA_kernel(const float* __restrict__ x,
                                                     const float* __restrict__ W,
                                                     unsigned short* __restrict__ hbf,
                                                     const void* __restrict__ ei,
                                                     int* __restrict__ coarse_cursor,
                                                     int* __restrict__ pairs, int E) {
    __shared__ __align__(16) char smem[FH * WP * 2];
    const int b = blockIdx.x;
    if (b < GA) gemm_role(x, W, hbf, b, smem);
    else        part_role(ei, coarse_cursor, pairs, E, b - GA, smem);
}

__global__ __launch_bounds__(256) void fusedB_kernel(const float* __restrict__ x,
                                                     const float* __restrict__ W,
                                                     unsigned short* __restrict__ hbf,
                                                     const int* __restrict__ pairs,
                                                     const int* __restrict__ coarse_cursor,
                                                     int* __restrict__ cursor,
                                                     float* __restrict__ dinv,
                                                     int* __restrict__ bucket) {
    __shared__ __align__(16) char smem[FH * WP * 2];
    const int b = blockIdx.x;
    if (b < GB) gemm_role(x, W, hbf, GA + b, smem);
    else        place_role(pairs, coarse_cursor, cursor, dinv, bucket, b - GB, smem);
}

// one wave per node, 8 edges in flight (proven R6/R9 form)
__global__ __launch_bounds__(256) void gather8_kernel(const unsigned short* __restrict__ hbf,
                                                      const float* __restrict__ dinv,
                                                      const int* __restrict__ cursor,
                                                      const int* __restrict__ bucket,
                                                      const float* __restrict__ b_conv,
                                                      float* __restrict__ ne) {
    const int node = blockIdx.x * 4 + (threadIdx.x >> 6);
    if (node >= NN) return;
    const int lane = threadIdx.x & 63;
    const int sub = lane & 7;
    const int eg = lane >> 3;

    const int base = cursor[node];
    const int end  = cursor[node + 1];
    const float dd = dinv[node];

    float acc[8] = {0,0,0,0,0,0,0,0};
    for (int k = base + eg; k < end; k += 8) {
        int s = bucket[k];
        float nrm = dinv[s] * dd;
        short8x hv = *(const short8x*)(hbf + (long long)s * FH + sub * 8);
#pragma unroll
        for (int j = 0; j < 8; ++j)
            acc[j] += bf2f((unsigned short)hv[j]) * nrm;
    }
#pragma unroll
    for (int m = 8; m < 64; m <<= 1) {
#pragma unroll
        for (int j = 0; j < 8; ++j) acc[j] += __shfl_xor(acc[j], m);
    }
    if (eg == 0) {
        short8x hs = *(const short8x*)(hbf + (long long)node * FH + sub * 8);
        float r[8];
#pragma unroll
        for (int j = 0; j < 8; ++j) {
            float v = acc[j] + bf2f((unsigned short)hs[j]) * dd * dd + b_conv[sub * 8 + j];
            r[j] = v >= 0.f ? v : NEG * v;
        }
        float4* o = (float4*)(ne + (long long)node * FH + sub * 8);
        o[0] = make_float4(r[0], r[1], r[2], r[3]);
        o[1] = make_float4(r[4], r[5], r[6], r[7]);
    }
}

// ------------------------- MLP head -----------------------------------------
__global__ __launch_bounds__(256) void mlp_kernel(const float* __restrict__ ne,
                                                  const void* __restrict__ idx,
                                                  const float* __restrict__ W1,
                                                  const float* __restrict__ b1,
                                                  const float* __restrict__ W2,
                                                  const float* __restrict__ b2,
                                                  float* __restrict__ out,
                                                  int B) {
    const int lane = threadIdx.x & 63;
    const int wid = threadIdx.x >> 6;
    const int is64 = is64_ballot(idx);

    float w1a[16], w1b[16], b1r[16], w2r[16];
#pragma unroll
    for (int o = 0; o < 16; ++o) {
        w1a[o] = W1[lane * 16 + o];
        w1b[o] = W1[(64 + lane) * 16 + o];
        b1r[o] = b1[o];
        w2r[o] = W2[o];
    }
    const float b2v = b2[0];

    for (int pair = blockIdx.x * 4 + wid; pair < B; pair += gridDim.x * 4) {
        long long i0 = load_idx(idx, 2LL * pair, is64);
        long long i1 = load_idx(idx, 2LL * pair + 1, is64);
        float a = ne[i0 * FH + lane];
        float b = ne[i1 * FH + lane];

        float acc[16];
#pragma unroll
        for (int o = 0; o < 16; ++o) acc[o] = a * w1a[o] + b * w1b[o];
#pragma unroll
        for (int m = 1; m < 64; m <<= 1) {
#pragma unroll
            for (int o = 0; o < 16; ++o) acc[o] += __shfl_xor(acc[o], m, 64);
        }
        if (lane == 0) {
            float s = b2v;
#pragma unroll
            for (int o = 0; o < 16; ++o) {
                float z = acc[o] + b1r[o];
                z = z >= 0.f ? z : NEG * z;
                s += z * w2r[o];
            }
            out[pair] = 1.f / (1.f + expf(-s));
        }
    }
}

// ------------------------- fallback (round-1) path --------------------------

__global__ void detect_kernel(const int* __restrict__ ei32, int* __restrict__ flag) {
    if (blockIdx.x == 0 && threadIdx.x == 0) {
        int ok = 1;
        for (int k = 0; k < 64; ++k)
            if (ei32[2 * k + 1] != 0) { ok = 0; break; }
        *flag = ok;
    }
}

__global__ __launch_bounds__(256) void gemm_kernel(const float* __restrict__ x,
                                                   const float* __restrict__ W,
                                                   float* __restrict__ h) {
    __shared__ float xs[4 * FIN];
    __shared__ float part[4][4][FH];

    const int col = threadIdx.x & 63;
    const int kseg = threadIdx.x >> 6;

    float wreg[64];
#pragma unroll
    for (int kk = 0; kk < 64; ++kk)
        wreg[kk] = W[(kseg * 64 + kk) * FH + col];

    for (int row0 = blockIdx.x * 4; row0 < NN; row0 += gridDim.x * 4) {
        const float4* xv = (const float4*)(x + (long long)row0 * FIN);
        ((float4*)xs)[threadIdx.x] = xv[threadIdx.x];
        __syncthreads();

        float acc[4] = {0.f, 0.f, 0.f, 0.f};
#pragma unroll
        for (int kk = 0; kk < 64; ++kk) {
            const float w = wreg[kk];
            const int k = kseg * 64 + kk;
#pragma unroll
            for (int r = 0; r < 4; ++r)
                acc[r] += xs[r * FIN + k] * w;
        }
#pragma unroll
        for (int r = 0; r < 4; ++r) part[r][kseg][col] = acc[r];
        __syncthreads();

        const int row = threadIdx.x >> 6;
        float s = part[row][0][col] + part[row][1][col] + part[row][2][col] + part[row][3][col];
        h[(long long)(row0 + row) * FH + col] = s;
        __syncthreads();
    }
}

__global__ __launch_bounds__(256) void init_kernel(float* __restrict__ ne,
                                                   float* __restrict__ deg,
                                                   const float* __restrict__ b_conv) {
    int idx = blockIdx.x * 256 + threadIdx.x;
    if (idx < NN * FH) ne[idx] = b_conv[idx & (FH - 1)];
    if (idx < NN) deg[idx] = 1.0f;
}

__global__ __launch_bounds__(256) void deg_kernel(const void* __restrict__ ei,
                                                  float* __restrict__ deg,
                                                  int E, const int* __restrict__ flag) {
    int e = blockIdx.x * 256 + threadIdx.x;
    if (e >= E) return;
    long long d = load_idx(ei, (long long)E + e, *flag);
    atomicAdd(&deg[d], 1.0f);
}

__global__ __launch_bounds__(256) void rsqrt_kernel(float* __restrict__ deg) {
    int i = blockIdx.x * 256 + threadIdx.x;
    if (i < NN) deg[i] = rsqrtf(deg[i]);
}

__global__ __launch_bounds__(256) void selfloop_kernel(const float* __restrict__ h,
                                                       const float* __restrict__ dinv,
                                                       float* __restrict__ ne) {
    int idx = blockIdx.x * 256 + threadIdx.x;
    if (idx >= NN * FH) return;
    int i = idx >> 6;
    float di = dinv[i];
    ne[idx] += h[idx] * di * di;
}

__global__ __launch_bounds__(256) void edge_agg_kernel(const void* __restrict__ ei,
                                                       const float* __restrict__ dinv,
                                                       const float* __restrict__ h,
                                                       float* __restrict__ ne,
                                                       int E, const int* __restrict__ flag) {
    long long t = (long long)blockIdx.x * 256 + threadIdx.x;
    long long e = t >> 4;
    int sub = (int)(t & 15);
    if (e >= E) return;
    int is64 = *flag;
    long long s = load_idx(ei, e, is64);
    long long d = load_idx(ei, (long long)E + e, is64);
    float nrm = dinv[s] * dinv[d];
    float4 hv = *(const float4*)(h + s * FH + sub * 4);
    float* np_ = ne + d * FH + sub * 4;
    atomicAdd(np_ + 0, hv.x * nrm);
    atomicAdd(np_ + 1, hv.y * nrm);
    atomicAdd(np_ + 2, hv.z * nrm);
    atomicAdd(np_ + 3, hv.w * nrm);
}

__global__ __launch_bounds__(256) void mlp_fb_kernel(const float* __restrict__ ne,
                                                     const void* __restrict__ idx,
                                                     const float* __restrict__ W1,
                                                     const float* __restrict__ b1,
                                                     const float* __restrict__ W2,
                                                     const float* __restrict__ b2,
                                                     float* __restrict__ out,
                                                     int B, const int* __restrict__ flag) {
    const int lane = threadIdx.x & 63;
    const int wid = threadIdx.x >> 6;

    float w1a[16], w1b[16], b1r[16], w2r[16];
#pragma unroll
    for (int o = 0; o < 16; ++o) {
        w1a[o] = W1[lane * 16 + o];
        w1b[o] = W1[(64 + lane) * 16 + o];
        b1r[o] = b1[o];
        w2r[o] = W2[o];
    }
    const float b2v = b2[0];
    const int is64 = *flag;

    for (int pair = blockIdx.x * 4 + wid; pair < B; pair += gridDim.x * 4) {
        long long i0 = load_idx(idx, 2LL * pair, is64);
        long long i1 = load_idx(idx, 2LL * pair + 1, is64);
        float a = ne[i0 * FH + lane];
        float b = ne[i1 * FH + lane];
        a = a >= 0.f ? a : NEG * a;
        b = b >= 0.f ? b : NEG * b;

        float acc[16];
#pragma unroll
        for (int o = 0; o < 16; ++o) acc[o] = a * w1a[o] + b * w1b[o];
#pragma unroll
        for (int m = 1; m < 64; m <<= 1) {
#pragma unroll
            for (int o = 0; o < 16; ++o) acc[o] += __shfl_xor(acc[o], m, 64);
        }
        if (lane == 0) {
            float s = b2v;
#pragma unroll
            for (int o = 0; o < 16; ++o) {
                float z = acc[o] + b1r[o];
                z = z >= 0.f ? z : NEG * z;
                s += z * w2r[o];
            }
            out[pair] = 1.f / (1.f + expf(-s));
        }
    }
}

extern "C" void kernel_launch(void* const* d_in, const int* in_sizes, int n_in,
                              void* d_out, int out_size, void* d_ws, size_t ws_size,
                              hipStream_t stream) {
    const float* x      = (const float*)d_in[0];
    const void*  ei     = d_in[1];
    const void*  index  = d_in[2];
    const float* W_conv = (const float*)d_in[3];
    const float* b_conv = (const float*)d_in[4];
    const float* W1     = (const float*)d_in[5];
    const float* b1     = (const float*)d_in[6];
    const float* W2     = (const float*)d_in[7];
    const float* b2     = (const float*)d_in[8];
    float* out = (float*)d_out;

    const int E = in_sizes[1] / 2;   // 1.6M
    const int B = in_sizes[2] / 2;   // 16384

    const size_t need_new = (size_t)NN * FH * 2
                          + ((size_t)NN * FH + NN + (NN + 1) + (size_t)E + NBUCK) * 4;

    if (ws_size >= need_new && (size_t)NBUCK * SLAB <= (size_t)NN * FH) {
        unsigned short* hbf = (unsigned short*)d_ws;
        float* ne       = (float*)(hbf + (long long)NN * FH);
        float* dinv     = ne + (long long)NN * FH;
        int*   cursor   = (int*)(dinv + NN);          // NN+1 entries
        int*   bucket   = cursor + (NN + 1);
        int*   coarse_cursor = bucket + E;            // NBUCK
        int*   pairs    = (int*)ne;                   // slab array in dead ne buffer

        const int npart = (E + P1_CH - 1) / P1_CH;

        zero_slab_kernel<<<1, 256, 0, stream>>>(coarse_cursor);
        fusedA_kernel<<<GA + npart, 256, 0, stream>>>(x, W_conv, hbf, ei, coarse_cursor, pairs, E);
        fusedB_kernel<<<GB + NBUCK, 256, 0, stream>>>(x, W_conv, hbf, pairs, coarse_cursor, cursor, dinv, bucket);
        gather8_kernel<<<(NN + 3) / 4, 256, 0, stream>>>(hbf, dinv, cursor, bucket, b_conv, ne);
        mlp_kernel<<<512, 256, 0, stream>>>(ne, index, W1, b1, W2, b2, out, B);
    } else {
        // fallback: round-1 atomic scatter (fp32)
        float* h   = (float*)d_ws;
        float* ne  = h + (long long)NN * FH;
        float* deg = ne + (long long)NN * FH;
        int* flag  = (int*)(deg + NN);

        detect_kernel<<<1, 64, 0, stream>>>((const int*)ei, flag);
        init_kernel<<<(NN * FH + 255) / 256, 256, 0, stream>>>(ne, deg, b_conv);
        gemm_kernel<<<2048, 256, 0, stream>>>(x, W_conv, h);
        deg_kernel<<<(E + 255) / 256, 256, 0, stream>>>(ei, deg, E, flag);
        rsqrt_kernel<<<(NN + 255) / 256, 256, 0, stream>>>(deg);
        selfloop_kernel<<<(NN * FH + 255) / 256, 256, 0, stream>>>(h, deg, ne);
        edge_agg_kernel<<<(int)(((long long)E * 16 + 255) / 256), 256, 0, stream>>>(ei, deg, h, ne, E, flag);
        mlp_fb_kernel<<<512, 256, 0, stream>>>(ne, index, W1, b1, W2, b2, out, B, flag);
    }
}

// Round 13
// 119.944 us; speedup vs baseline: 1.4325x; 1.2559x over previous
//
#include <hip/hip_runtime.h>
#include <hip/hip_bf16.h>

#define NN 100000      // nodes
#define FIN 256        // input features
#define FH 64          // hidden features
#define NEG 0.01f
#define NBUCK 256
#define BNODES ((NN + NBUCK - 1) / NBUCK)          // 391 nodes per coarse bucket
#define P1_CH 4096
#define WP 264         // LDS pitch for W^T (bf16 elems)
#define SRCMASK 0x1FFFF   // 17 bits (NN < 131072)
#define SLAB 16384     // slab capacity per coarse bucket (mean fill ~6250)
#define GA 782         // gemm blocks (64 rows each) in fusedA
#define GB 781         // gemm blocks in fusedB  (782+781 = 1563 = ceil(NN/64))

typedef __attribute__((ext_vector_type(8))) short short8x;
typedef __attribute__((ext_vector_type(4))) float f32x4;

__device__ inline unsigned short f2bf_hw(float f) {
    __hip_bfloat16 h = __float2bfloat16(f);
    return __builtin_bit_cast(unsigned short, h);
}
__device__ inline float bf2f(unsigned short s) {
    return __uint_as_float(((unsigned)s) << 16);
}

__device__ inline long long load_idx(const void* p, long long i, int is64) {
    if (is64) return ((const long long*)p)[i];
    return (long long)((const int*)p)[i];
}

// wave-ballot int64 detection: hi-words of first 64 entries all zero => int64
__device__ inline int is64_ballot(const void* p) {
    const int* p32 = (const int*)p;
    int lane = threadIdx.x & 63;
    int ok = (p32[2 * lane + 1] == 0) ? 1 : 0;
    unsigned long long m = __ballot(ok);
    return m == ~0ULL ? 1 : 0;
}

// ---------------------------------------------------------------------------
// ws layout (CSR path), bytes:
//   hbf[NN*FH] bf16 | ne[NN*FH] f32 (pairs slab int[NBUCK*SLAB] staged here) |
//   dinv[NN] | cursor[NN+1] | bucket[E] | coarse_cursor[NBUCK] | flags[NN] u8
// Fallback (ws too small): h f32 | ne f32 | deg | flag  (round-1 scatter)
// ---------------------------------------------------------------------------

// block 0: slab cursor init; blocks 1..: zero needed-node flags
__global__ __launch_bounds__(256) void prep_kernel(int* __restrict__ coarse_cursor,
                                                   unsigned char* __restrict__ flags) {
    const int b = blockIdx.x, t = threadIdx.x;
    if (b == 0) {
        coarse_cursor[t] = t * SLAB;
    } else {
        int i = (b - 1) * 256 + t;
        if (i < NN) flags[i] = 0;
    }
}

// ---------------- gemm role: 64 rows of hbf = bf16(x @ W_conv) --------------
__device__ void gemm_role(const float* __restrict__ x, const float* __restrict__ W,
                          unsigned short* __restrict__ hbf, int gb, char* smem) {
    unsigned short* Wt = (unsigned short*)smem;   // [col][k], pitch WP

    for (int i = threadIdx.x; i < FIN * FH; i += 256) {
        int k = i >> 6, c = i & 63;
        Wt[c * WP + k] = f2bf_hw(W[i]);
    }
    __syncthreads();

    const int wv = threadIdx.x >> 6;
    const int lane = threadIdx.x & 63;
    const int c = lane & 15;
    const int eg = lane >> 4;

    const int row0 = (gb * 4 + wv) * 16;
    int rowA = row0 + c;
    if (rowA >= NN) rowA = NN - 1;
    const float* aptr = x + (long long)rowA * FIN;

    f32x4 acc[4] = {{0,0,0,0},{0,0,0,0},{0,0,0,0},{0,0,0,0}};

#pragma unroll
    for (int kk = 0; kk < 8; ++kk) {
        const int kbase = kk * 32 + eg * 8;
        float4 f0 = *(const float4*)(aptr + kbase);
        float4 f1 = *(const float4*)(aptr + kbase + 4);
        short8x a;
        a[0] = (short)f2bf_hw(f0.x); a[1] = (short)f2bf_hw(f0.y);
        a[2] = (short)f2bf_hw(f0.z); a[3] = (short)f2bf_hw(f0.w);
        a[4] = (short)f2bf_hw(f1.x); a[5] = (short)f2bf_hw(f1.y);
        a[6] = (short)f2bf_hw(f1.z); a[7] = (short)f2bf_hw(f1.w);
#pragma unroll
        for (int cb = 0; cb < 4; ++cb) {
            short8x b = *(const short8x*)(&Wt[(cb * 16 + c) * WP + kbase]);
            acc[cb] = __builtin_amdgcn_mfma_f32_16x16x32_bf16(a, b, acc[cb], 0, 0, 0);
        }
    }

#pragma unroll
    for (int cb = 0; cb < 4; ++cb) {
#pragma unroll
        for (int r = 0; r < 4; ++r) {
            int rowO = row0 + eg * 4 + r;
            if (rowO < NN)
                hbf[(long long)rowO * FH + cb * 16 + c] = f2bf_hw(acc[cb][r]);
        }
    }
}

// ---------------- part role: direct slab partition (no precount) ------------
__device__ void part_role(const void* __restrict__ ei, int* __restrict__ coarse_cursor,
                          int* __restrict__ pairs, int E, int pb, char* smem) {
    int* hist = (int*)smem;
    int* blkoff = hist + NBUCK;
    const int t = threadIdx.x;
    hist[t] = 0;
    __syncthreads();
    const int is64 = is64_ballot(ei);
    const long long base = (long long)pb * P1_CH;

    int pkv[16], bkt[16], rnk[16];
#pragma unroll
    for (int i = 0; i < 16; ++i) {
        long long e = base + i * 256 + t;
        if (e < E) {
            int s = (int)load_idx(ei, e, is64);
            int d = (int)load_idx(ei, (long long)E + e, is64);
            int b = (int)((unsigned)d / BNODES);
            int dl = d - b * BNODES;
            pkv[i] = s | (dl << 17);
            bkt[i] = b;
            rnk[i] = atomicAdd(&hist[b], 1);
        } else {
            bkt[i] = -1;
        }
    }
    __syncthreads();
    blkoff[t] = atomicAdd(&coarse_cursor[t], hist[t]);
    __syncthreads();
#pragma unroll
    for (int i = 0; i < 16; ++i) {
        if (bkt[i] >= 0) {
            int pos = blkoff[bkt[i]] + rnk[i];
            if (pos < (bkt[i] + 1) * SLAB)   // overflow clamp (never hit: uniform dst)
                pairs[pos] = pkv[i];
        }
    }
}

// ---------------- mark role: set flags for MLP-needed nodes -----------------
__device__ void mark_role(const void* __restrict__ idx, unsigned char* __restrict__ flags,
                          int nIdx, int mb) {
    const int is64 = is64_ballot(idx);
    int i = mb * 256 + threadIdx.x;
    if (i < nIdx) flags[load_idx(idx, i, is64)] = 1;
}

// ---------------- place role: full degree count, filtered placement ---------
__device__ void place_role(const int* __restrict__ pairs,
                           const int* __restrict__ coarse_cursor,
                           int* __restrict__ cursor, float* __restrict__ dinv,
                           int* __restrict__ bucket,
                           const unsigned char* __restrict__ flags,
                           int b, char* smem) {
    int* cnt = (int*)smem;                     // BNODES
    int* nstart = cnt + BNODES;                // BNODES+1
    int* wsum = nstart + BNODES + 1;           // 8 (padded)
    int* sh = wsum + 8;                        // 2: lo, cntb
    unsigned char* nflag = (unsigned char*)(sh + 2);  // BNODES
    const int t = threadIdx.x;
    const int lane = t & 63, w = t >> 6;

    // per-bucket counts from slab cursors; block-wide exclusive scan
    int myc = coarse_cursor[t] - t * SLAB;
    if (myc > SLAB) myc = SLAB;
    int incl0 = myc;
#pragma unroll
    for (int m = 1; m < 64; m <<= 1) {
        int u = __shfl_up(incl0, m, 64);
        if (lane >= m) incl0 += u;
    }
    if (lane == 63) wsum[w] = incl0;
    __syncthreads();
    int woff0 = 0;
    for (int i = 0; i < w; ++i) woff0 += wsum[i];
    int ex0 = woff0 + incl0 - myc;
    if (t == b) { sh[0] = ex0; sh[1] = myc; }
    __syncthreads();
    const int lo = sh[0];
    const int cntb = sh[1];
    const int g0 = b * BNODES;
    const int nb = (NN - g0 < BNODES) ? (NN - g0) : BNODES;
    const int sb = b * SLAB;

    for (int j = t; j < nb; j += 256) {
        cnt[j] = 0;
        nflag[j] = flags[g0 + j];
    }
    __syncthreads();

    // pass 1: FULL local degree count (dinv needs true degrees)
    for (int i = t; i < cntb; i += 256)
        atomicAdd(&cnt[pairs[sb + i] >> 17], 1);
    __syncthreads();

    // exclusive scan of cnt[0..nb) -> nstart[0..nb]  (full CSR layout)
    const int i0 = 2 * t, i1 = 2 * t + 1;
    const int v0 = (i0 < nb) ? cnt[i0] : 0;
    const int v1 = (i1 < nb) ? cnt[i1] : 0;
    const int s = v0 + v1;
    int incl = s;
#pragma unroll
    for (int m = 1; m < 64; m <<= 1) {
        int u = __shfl_up(incl, m, 64);
        if (lane >= m) incl += u;
    }
    __syncthreads();           // protect wsum reuse
    if (lane == 63) wsum[w] = incl;
    __syncthreads();
    int woff = 0;
    for (int i = 0; i < w; ++i) woff += wsum[i];
    const int ex = woff + incl - s;
    if (i0 <= nb) nstart[i0] = ex;
    if (i1 <= nb) nstart[i1] = ex + v0;
    __syncthreads();

    // emit cursor + dinv (coalesced, full)
    for (int j = t; j <= nb; j += 256) {
        int g = g0 + j;
        if (g <= NN) cursor[g] = lo + nstart[j];
    }
    for (int j = t; j < nb; j += 256)
        dinv[g0 + j] = rsqrtf(1.0f + (float)(nstart[j + 1] - nstart[j]));

    // pass 2: place ONLY edges whose dst is MLP-needed
    for (int j = t; j < nb; j += 256) cnt[j] = 0;
    __syncthreads();
    for (int i = t; i < cntb; i += 256) {
        int p = pairs[sb + i];
        int local = p >> 17;
        if (nflag[local]) {
            int r = atomicAdd(&cnt[local], 1);
            bucket[lo + nstart[local] + r] = p & SRCMASK;
        }
    }
}

// ---------------- fused kernels (block-range dispatch) ----------------------
__global__ __launch_bounds__(256) void fusedA_kernel(const float* __restrict__ x,
                                                     const float* __restrict__ W,
                                                     unsigned short* __restrict__ hbf,
                                                     const void* __restrict__ ei,
                                                     int* __restrict__ coarse_cursor,
                                                     int* __restrict__ pairs, int E,
                                                     const void* __restrict__ idx,
                                                     unsigned char* __restrict__ flags,
                                                     int nIdx, int npart) {
    __shared__ __align__(16) char smem[FH * WP * 2];
    const int b = blockIdx.x;
    if (b < GA)              gemm_role(x, W, hbf, b, smem);
    else if (b < GA + npart) part_role(ei, coarse_cursor, pairs, E, b - GA, smem);
    else                     mark_role(idx, flags, nIdx, b - GA - npart);
}

__global__ __launch_bounds__(256) void fusedB_kernel(const float* __restrict__ x,
                                                     const float* __restrict__ W,
                                                     unsigned short* __restrict__ hbf,
                                                     const int* __restrict__ pairs,
                                                     const int* __restrict__ coarse_cursor,
                                                     int* __restrict__ cursor,
                                                     float* __restrict__ dinv,
                                                     int* __restrict__ bucket,
                                                     const unsigned char* __restrict__ flags) {
    __shared__ __align__(16) char smem[FH * WP * 2];
    const int b = blockIdx.x;
    if (b < GB) gemm_role(x, W, hbf, GA + b, smem);
    else        place_role(pairs, coarse_cursor, cursor, dinv, bucket, flags, b - GB, smem);
}

// one wave per node, 8 edges in flight; skip nodes the MLP never reads
__global__ __launch_bounds__(256) void gather8_kernel(const unsigned short* __restrict__ hbf,
                                                      const float* __restrict__ dinv,
                                                      const int* __restrict__ cursor,
                                                      const int* __restrict__ bucket,
                                                      const float* __restrict__ b_conv,
                                                      const unsigned char* __restrict__ flags,
                                                      float* __restrict__ ne) {
    const int node = blockIdx.x * 4 + (threadIdx.x >> 6);
    if (node >= NN) return;
    if (!flags[node]) return;          // per-wave early exit (no syncthreads below)
    const int lane = threadIdx.x & 63;
    const int sub = lane & 7;
    const int eg = lane >> 3;

    const int base = cursor[node];
    const int end  = cursor[node + 1];
    const float dd = dinv[node];

    float acc[8] = {0,0,0,0,0,0,0,0};
    for (int k = base + eg; k < end; k += 8) {
        int s = bucket[k];
        float nrm = dinv[s] * dd;
        short8x hv = *(const short8x*)(hbf + (long long)s * FH + sub * 8);
#pragma unroll
        for (int j = 0; j < 8; ++j)
            acc[j] += bf2f((unsigned short)hv[j]) * nrm;
    }
#pragma unroll
    for (int m = 8; m < 64; m <<= 1) {
#pragma unroll
        for (int j = 0; j < 8; ++j) acc[j] += __shfl_xor(acc[j], m);
    }
    if (eg == 0) {
        short8x hs = *(const short8x*)(hbf + (long long)node * FH + sub * 8);
        float r[8];
#pragma unroll
        for (int j = 0; j < 8; ++j) {
            float v = acc[j] + bf2f((unsigned short)hs[j]) * dd * dd + b_conv[sub * 8 + j];
            r[j] = v >= 0.f ? v : NEG * v;
        }
        float4* o = (float4*)(ne + (long long)node * FH + sub * 8);
        o[0] = make_float4(r[0], r[1], r[2], r[3]);
        o[1] = make_float4(r[4], r[5], r[6], r[7]);
    }
}

// ------------------------- MLP head -----------------------------------------
__global__ __launch_bounds__(256) void mlp_kernel(const float* __restrict__ ne,
                                                  const void* __restrict__ idx,
                                                  const float* __restrict__ W1,
                                                  const float* __restrict__ b1,
                                                  const float* __restrict__ W2,
                                                  const float* __restrict__ b2,
                                                  float* __restrict__ out,
                                                  int B) {
    const int lane = threadIdx.x & 63;
    const int wid = threadIdx.x >> 6;
    const int is64 = is64_ballot(idx);

    float w1a[16], w1b[16], b1r[16], w2r[16];
#pragma unroll
    for (int o = 0; o < 16; ++o) {
        w1a[o] = W1[lane * 16 + o];
        w1b[o] = W1[(64 + lane) * 16 + o];
        b1r[o] = b1[o];
        w2r[o] = W2[o];
    }
    const float b2v = b2[0];

    for (int pair = blockIdx.x * 4 + wid; pair < B; pair += gridDim.x * 4) {
        long long i0 = load_idx(idx, 2LL * pair, is64);
        long long i1 = load_idx(idx, 2LL * pair + 1, is64);
        float a = ne[i0 * FH + lane];
        float b = ne[i1 * FH + lane];

        float acc[16];
#pragma unroll
        for (int o = 0; o < 16; ++o) acc[o] = a * w1a[o] + b * w1b[o];
#pragma unroll
        for (int m = 1; m < 64; m <<= 1) {
#pragma unroll
            for (int o = 0; o < 16; ++o) acc[o] += __shfl_xor(acc[o], m, 64);
        }
        if (lane == 0) {
            float s = b2v;
#pragma unroll
            for (int o = 0; o < 16; ++o) {
                float z = acc[o] + b1r[o];
                z = z >= 0.f ? z : NEG * z;
                s += z * w2r[o];
            }
            out[pair] = 1.f / (1.f + expf(-s));
        }
    }
}

// ------------------------- fallback (round-1) path --------------------------

__global__ void detect_kernel(const int* __restrict__ ei32, int* __restrict__ flag) {
    if (blockIdx.x == 0 && threadIdx.x == 0) {
        int ok = 1;
        for (int k = 0; k < 64; ++k)
            if (ei32[2 * k + 1] != 0) { ok = 0; break; }
        *flag = ok;
    }
}

__global__ __launch_bounds__(256) void gemm_kernel(const float* __restrict__ x,
                                                   const float* __restrict__ W,
                                                   float* __restrict__ h) {
    __shared__ float xs[4 * FIN];
    __shared__ float part[4][4][FH];

    const int col = threadIdx.x & 63;
    const int kseg = threadIdx.x >> 6;

    float wreg[64];
#pragma unroll
    for (int kk = 0; kk < 64; ++kk)
        wreg[kk] = W[(kseg * 64 + kk) * FH + col];

    for (int row0 = blockIdx.x * 4; row0 < NN; row0 += gridDim.x * 4) {
        const float4* xv = (const float4*)(x + (long long)row0 * FIN);
        ((float4*)xs)[threadIdx.x] = xv[threadIdx.x];
        __syncthreads();

        float acc[4] = {0.f, 0.f, 0.f, 0.f};
#pragma unroll
        for (int kk = 0; kk < 64; ++kk) {
            const float w = wreg[kk];
            const int k = kseg * 64 + kk;
#pragma unroll
            for (int r = 0; r < 4; ++r)
                acc[r] += xs[r * FIN + k] * w;
        }
#pragma unroll
        for (int r = 0; r < 4; ++r) part[r][kseg][col] = acc[r];
        __syncthreads();

        const int row = threadIdx.x >> 6;
        float s = part[row][0][col] + part[row][1][col] + part[row][2][col] + part[row][3][col];
        h[(long long)(row0 + row) * FH + col] = s;
        __syncthreads();
    }
}

__global__ __launch_bounds__(256) void init_kernel(float* __restrict__ ne,
                                                   float* __restrict__ deg,
                                                   const float* __restrict__ b_conv) {
    int idx = blockIdx.x * 256 + threadIdx.x;
    if (idx < NN * FH) ne[idx] = b_conv[idx & (FH - 1)];
    if (idx < NN) deg[idx] = 1.0f;
}

__global__ __launch_bounds__(256) void deg_kernel(const void* __restrict__ ei,
                                                  float* __restrict__ deg,
                                                  int E, const int* __restrict__ flag) {
    int e = blockIdx.x * 256 + threadIdx.x;
    if (e >= E) return;
    long long d = load_idx(ei, (long long)E + e, *flag);
    atomicAdd(&deg[d], 1.0f);
}

__global__ __launch_bounds__(256) void rsqrt_kernel(float* __restrict__ deg) {
    int i = blockIdx.x * 256 + threadIdx.x;
    if (i < NN) deg[i] = rsqrtf(deg[i]);
}

__global__ __launch_bounds__(256) void selfloop_kernel(const float* __restrict__ h,
                                                       const float* __restrict__ dinv,
                                                       float* __restrict__ ne) {
    int idx = blockIdx.x * 256 + threadIdx.x;
    if (idx >= NN * FH) return;
    int i = idx >> 6;
    float di = dinv[i];
    ne[idx] += h[idx] * di * di;
}

__global__ __launch_bounds__(256) void edge_agg_kernel(const void* __restrict__ ei,
                                                       const float* __restrict__ dinv,
                                                       const float* __restrict__ h,
                                                       float* __restrict__ ne,
                                                       int E, const int* __restrict__ flag) {
    long long t = (long long)blockIdx.x * 256 + threadIdx.x;
    long long e = t >> 4;
    int sub = (int)(t & 15);
    if (e >= E) return;
    int is64 = *flag;
    long long s = load_idx(ei, e, is64);
    long long d = load_idx(ei, (long long)E + e, is64);
    float nrm = dinv[s] * dinv[d];
    float4 hv = *(const float4*)(h + s * FH + sub * 4);
    float* np_ = ne + d * FH + sub * 4;
    atomicAdd(np_ + 0, hv.x * nrm);
    atomicAdd(np_ + 1, hv.y * nrm);
    atomicAdd(np_ + 2, hv.z * nrm);
    atomicAdd(np_ + 3, hv.w * nrm);
}

__global__ __launch_bounds__(256) void mlp_fb_kernel(const float* __restrict__ ne,
                                                     const void* __restrict__ idx,
                                                     const float* __restrict__ W1,
                                                     const float* __restrict__ b1,
                                                     const float* __restrict__ W2,
                                                     const float* __restrict__ b2,
                                                     float* __restrict__ out,
                                                     int B, const int* __restrict__ flag) {
    const int lane = threadIdx.x & 63;
    const int wid = threadIdx.x >> 6;

    float w1a[16], w1b[16], b1r[16], w2r[16];
#pragma unroll
    for (int o = 0; o < 16; ++o) {
        w1a[o] = W1[lane * 16 + o];
        w1b[o] = W1[(64 + lane) * 16 + o];
        b1r[o] = b1[o];
        w2r[o] = W2[o];
    }
    const float b2v = b2[0];
    const int is64 = *flag;

    for (int pair = blockIdx.x * 4 + wid; pair < B; pair += gridDim.x * 4) {
        long long i0 = load_idx(idx, 2LL * pair, is64);
        long long i1 = load_idx(idx, 2LL * pair + 1, is64);
        float a = ne[i0 * FH + lane];
        float b = ne[i1 * FH + lane];
        a = a >= 0.f ? a : NEG * a;
        b = b >= 0.f ? b : NEG * b;

        float acc[16];
#pragma unroll
        for (int o = 0; o < 16; ++o) acc[o] = a * w1a[o] + b * w1b[o];
#pragma unroll
        for (int m = 1; m < 64; m <<= 1) {
#pragma unroll
            for (int o = 0; o < 16; ++o) acc[o] += __shfl_xor(acc[o], m, 64);
        }
        if (lane == 0) {
            float s = b2v;
#pragma unroll
            for (int o = 0; o < 16; ++o) {
                float z = acc[o] + b1r[o];
                z = z >= 0.f ? z : NEG * z;
                s += z * w2r[o];
            }
            out[pair] = 1.f / (1.f + expf(-s));
        }
    }
}

extern "C" void kernel_launch(void* const* d_in, const int* in_sizes, int n_in,
                              void* d_out, int out_size, void* d_ws, size_t ws_size,
                              hipStream_t stream) {
    const float* x      = (const float*)d_in[0];
    const void*  ei     = d_in[1];
    const void*  index  = d_in[2];
    const float* W_conv = (const float*)d_in[3];
    const float* b_conv = (const float*)d_in[4];
    const float* W1     = (const float*)d_in[5];
    const float* b1     = (const float*)d_in[6];
    const float* W2     = (const float*)d_in[7];
    const float* b2     = (const float*)d_in[8];
    float* out = (float*)d_out;

    const int E = in_sizes[1] / 2;   // 1.6M
    const int B = in_sizes[2] / 2;   // 16384

    const size_t need_new = (size_t)NN * FH * 2
                          + ((size_t)NN * FH + NN + (NN + 1) + (size_t)E + NBUCK) * 4
                          + NN;      // flags

    if (ws_size >= need_new && (size_t)NBUCK * SLAB <= (size_t)NN * FH) {
        unsigned short* hbf = (unsigned short*)d_ws;
        float* ne       = (float*)(hbf + (long long)NN * FH);
        float* dinv     = ne + (long long)NN * FH;
        int*   cursor   = (int*)(dinv + NN);          // NN+1 entries
        int*   bucket   = cursor + (NN + 1);
        int*   coarse_cursor = bucket + E;            // NBUCK
        unsigned char* flags = (unsigned char*)(coarse_cursor + NBUCK);
        int*   pairs    = (int*)ne;                   // slab array in dead ne buffer

        const int npart = (E + P1_CH - 1) / P1_CH;
        const int nmark = (2 * B + 255) / 256;

        prep_kernel<<<1 + (NN + 255) / 256, 256, 0, stream>>>(coarse_cursor, flags);
        fusedA_kernel<<<GA + npart + nmark, 256, 0, stream>>>(x, W_conv, hbf, ei,
                                                              coarse_cursor, pairs, E,
                                                              index, flags, 2 * B, npart);
        fusedB_kernel<<<GB + NBUCK, 256, 0, stream>>>(x, W_conv, hbf, pairs, coarse_cursor,
                                                      cursor, dinv, bucket, flags);
        gather8_kernel<<<(NN + 3) / 4, 256, 0, stream>>>(hbf, dinv, cursor, bucket,
                                                         b_conv, flags, ne);
        mlp_kernel<<<512, 256, 0, stream>>>(ne, index, W1, b1, W2, b2, out, B);
    } else {
        // fallback: round-1 atomic scatter (fp32)
        float* h   = (float*)d_ws;
        float* ne  = h + (long long)NN * FH;
        float* deg = ne + (long long)NN * FH;
        int* flag  = (int*)(deg + NN);

        detect_kernel<<<1, 64, 0, stream>>>((const int*)ei, flag);
        init_kernel<<<(NN * FH + 255) / 256, 256, 0, stream>>>(ne, deg, b_conv);
        gemm_kernel<<<2048, 256, 0, stream>>>(x, W_conv, h);
        deg_kernel<<<(E + 255) / 256, 256, 0, stream>>>(ei, deg, E, flag);
        rsqrt_kernel<<<(NN + 255) / 256, 256, 0, stream>>>(deg);
        selfloop_kernel<<<(NN * FH + 255) / 256, 256, 0, stream>>>(h, deg, ne);
        edge_agg_kernel<<<(int)(((long long)E * 16 + 255) / 256), 256, 0, stream>>>(ei, deg, h, ne, E, flag);
        mlp_fb_kernel<<<512, 256, 0, stream>>>(ne, index, W1, b1, W2, b2, out, B, flag);
    }
}

// Round 14
// 103.757 us; speedup vs baseline: 1.6559x; 1.1560x over previous
//
#include <hip/hip_runtime.h>
#include <hip/hip_bf16.h>

#define NN 100000      // nodes
#define FIN 256        // input features
#define FH 64          // hidden features
#define NEG 0.01f
#define NBUCK 256
#define BNODES ((NN + NBUCK - 1) / NBUCK)          // 391 nodes per coarse bucket
#define P1_CH 4096
#define WP 264         // LDS pitch for W^T (bf16 elems)
#define SRCMASK 0x1FFFF   // 17 bits (NN < 131072)
#define SLAB 16384     // slab capacity per coarse bucket (mean fill ~6250)
#define GA 782         // gemm blocks (64 rows each) in fusedA
#define GB 781         // gemm blocks in fusedB  (782+781 = 1563 = ceil(NN/64))

typedef __attribute__((ext_vector_type(8))) short short8x;
typedef __attribute__((ext_vector_type(4))) float f32x4;

__device__ inline unsigned short f2bf_hw(float f) {
    __hip_bfloat16 h = __float2bfloat16(f);
    return __builtin_bit_cast(unsigned short, h);
}
__device__ inline float bf2f(unsigned short s) {
    return __uint_as_float(((unsigned)s) << 16);
}

__device__ inline long long load_idx(const void* p, long long i, int is64) {
    if (is64) return ((const long long*)p)[i];
    return (long long)((const int*)p)[i];
}

// wave-ballot int64 detection: hi-words of first 64 entries all zero => int64
__device__ inline int is64_ballot(const void* p) {
    const int* p32 = (const int*)p;
    int lane = threadIdx.x & 63;
    int ok = (p32[2 * lane + 1] == 0) ? 1 : 0;
    unsigned long long m = __ballot(ok);
    return m == ~0ULL ? 1 : 0;
}

// ---------------------------------------------------------------------------
// ws layout (CSR path), bytes:
//   hbf[NN*FH] bf16 | scratch[NN*FH] f32 (pairs slab int[NBUCK*SLAB]) |
//   dinv[NN] | cursor[NN+1] | bucket[E] | coarse_cursor[NBUCK] | flags[NN] u8
// Fallback (ws too small): h f32 | ne f32 | deg | flag  (round-1 scatter)
// ---------------------------------------------------------------------------

// block 0: slab cursor init; blocks 1..: zero needed-node flags
__global__ __launch_bounds__(256) void prep_kernel(int* __restrict__ coarse_cursor,
                                                   unsigned char* __restrict__ flags) {
    const int b = blockIdx.x, t = threadIdx.x;
    if (b == 0) {
        coarse_cursor[t] = t * SLAB;
    } else {
        int i = (b - 1) * 256 + t;
        if (i < NN) flags[i] = 0;
    }
}

// ---------------- gemm role: 64 rows of hbf = bf16(x @ W_conv) --------------
__device__ void gemm_role(const float* __restrict__ x, const float* __restrict__ W,
                          unsigned short* __restrict__ hbf, int gb, char* smem) {
    unsigned short* Wt = (unsigned short*)smem;   // [col][k], pitch WP

    for (int i = threadIdx.x; i < FIN * FH; i += 256) {
        int k = i >> 6, c = i & 63;
        Wt[c * WP + k] = f2bf_hw(W[i]);
    }
    __syncthreads();

    const int wv = threadIdx.x >> 6;
    const int lane = threadIdx.x & 63;
    const int c = lane & 15;
    const int eg = lane >> 4;

    const int row0 = (gb * 4 + wv) * 16;
    int rowA = row0 + c;
    if (rowA >= NN) rowA = NN - 1;
    const float* aptr = x + (long long)rowA * FIN;

    f32x4 acc[4] = {{0,0,0,0},{0,0,0,0},{0,0,0,0},{0,0,0,0}};

#pragma unroll
    for (int kk = 0; kk < 8; ++kk) {
        const int kbase = kk * 32 + eg * 8;
        float4 f0 = *(const float4*)(aptr + kbase);
        float4 f1 = *(const float4*)(aptr + kbase + 4);
        short8x a;
        a[0] = (short)f2bf_hw(f0.x); a[1] = (short)f2bf_hw(f0.y);
        a[2] = (short)f2bf_hw(f0.z); a[3] = (short)f2bf_hw(f0.w);
        a[4] = (short)f2bf_hw(f1.x); a[5] = (short)f2bf_hw(f1.y);
        a[6] = (short)f2bf_hw(f1.z); a[7] = (short)f2bf_hw(f1.w);
#pragma unroll
        for (int cb = 0; cb < 4; ++cb) {
            short8x b = *(const short8x*)(&Wt[(cb * 16 + c) * WP + kbase]);
            acc[cb] = __builtin_amdgcn_mfma_f32_16x16x32_bf16(a, b, acc[cb], 0, 0, 0);
        }
    }

#pragma unroll
    for (int cb = 0; cb < 4; ++cb) {
#pragma unroll
        for (int r = 0; r < 4; ++r) {
            int rowO = row0 + eg * 4 + r;
            if (rowO < NN)
                hbf[(long long)rowO * FH + cb * 16 + c] = f2bf_hw(acc[cb][r]);
        }
    }
}

// ---------------- part role: direct slab partition (no precount) ------------
__device__ void part_role(const void* __restrict__ ei, int* __restrict__ coarse_cursor,
                          int* __restrict__ pairs, int E, int pb, char* smem) {
    int* hist = (int*)smem;
    int* blkoff = hist + NBUCK;
    const int t = threadIdx.x;
    hist[t] = 0;
    __syncthreads();
    const int is64 = is64_ballot(ei);
    const long long base = (long long)pb * P1_CH;

    int pkv[16], bkt[16], rnk[16];
#pragma unroll
    for (int i = 0; i < 16; ++i) {
        long long e = base + i * 256 + t;
        if (e < E) {
            int s = (int)load_idx(ei, e, is64);
            int d = (int)load_idx(ei, (long long)E + e, is64);
            int b = (int)((unsigned)d / BNODES);
            int dl = d - b * BNODES;
            pkv[i] = s | (dl << 17);
            bkt[i] = b;
            rnk[i] = atomicAdd(&hist[b], 1);
        } else {
            bkt[i] = -1;
        }
    }
    __syncthreads();
    blkoff[t] = atomicAdd(&coarse_cursor[t], hist[t]);
    __syncthreads();
#pragma unroll
    for (int i = 0; i < 16; ++i) {
        if (bkt[i] >= 0) {
            int pos = blkoff[bkt[i]] + rnk[i];
            if (pos < (bkt[i] + 1) * SLAB)   // overflow clamp (never hit: uniform dst)
                pairs[pos] = pkv[i];
        }
    }
}

// ---------------- mark role: set flags for MLP-needed nodes -----------------
__device__ void mark_role(const void* __restrict__ idx, unsigned char* __restrict__ flags,
                          int nIdx, int mb) {
    const int is64 = is64_ballot(idx);
    int i = mb * 256 + threadIdx.x;
    if (i < nIdx) flags[load_idx(idx, i, is64)] = 1;
}

// ---------------- place role: full degree count, filtered placement ---------
__device__ void place_role(const int* __restrict__ pairs,
                           const int* __restrict__ coarse_cursor,
                           int* __restrict__ cursor, float* __restrict__ dinv,
                           int* __restrict__ bucket,
                           const unsigned char* __restrict__ flags,
                           int b, char* smem) {
    int* cnt = (int*)smem;                     // BNODES
    int* nstart = cnt + BNODES;                // BNODES+1
    int* wsum = nstart + BNODES + 1;           // 8 (padded)
    int* sh = wsum + 8;                        // 2: lo, cntb
    unsigned char* nflag = (unsigned char*)(sh + 2);  // BNODES
    const int t = threadIdx.x;
    const int lane = t & 63, w = t >> 6;

    // per-bucket counts from slab cursors; block-wide exclusive scan
    int myc = coarse_cursor[t] - t * SLAB;
    if (myc > SLAB) myc = SLAB;
    int incl0 = myc;
#pragma unroll
    for (int m = 1; m < 64; m <<= 1) {
        int u = __shfl_up(incl0, m, 64);
        if (lane >= m) incl0 += u;
    }
    if (lane == 63) wsum[w] = incl0;
    __syncthreads();
    int woff0 = 0;
    for (int i = 0; i < w; ++i) woff0 += wsum[i];
    int ex0 = woff0 + incl0 - myc;
    if (t == b) { sh[0] = ex0; sh[1] = myc; }
    __syncthreads();
    const int lo = sh[0];
    const int cntb = sh[1];
    const int g0 = b * BNODES;
    const int nb = (NN - g0 < BNODES) ? (NN - g0) : BNODES;
    const int sb = b * SLAB;

    for (int j = t; j < nb; j += 256) {
        cnt[j] = 0;
        nflag[j] = flags[g0 + j];
    }
    __syncthreads();

    // pass 1: FULL local degree count (dinv needs true degrees)
    for (int i = t; i < cntb; i += 256)
        atomicAdd(&cnt[pairs[sb + i] >> 17], 1);
    __syncthreads();

    // exclusive scan of cnt[0..nb) -> nstart[0..nb]  (full CSR layout)
    const int i0 = 2 * t, i1 = 2 * t + 1;
    const int v0 = (i0 < nb) ? cnt[i0] : 0;
    const int v1 = (i1 < nb) ? cnt[i1] : 0;
    const int s = v0 + v1;
    int incl = s;
#pragma unroll
    for (int m = 1; m < 64; m <<= 1) {
        int u = __shfl_up(incl, m, 64);
        if (lane >= m) incl += u;
    }
    __syncthreads();           // protect wsum reuse
    if (lane == 63) wsum[w] = incl;
    __syncthreads();
    int woff = 0;
    for (int i = 0; i < w; ++i) woff += wsum[i];
    const int ex = woff + incl - s;
    if (i0 <= nb) nstart[i0] = ex;
    if (i1 <= nb) nstart[i1] = ex + v0;
    __syncthreads();

    // emit cursor + dinv (coalesced, full)
    for (int j = t; j <= nb; j += 256) {
        int g = g0 + j;
        if (g <= NN) cursor[g] = lo + nstart[j];
    }
    for (int j = t; j < nb; j += 256)
        dinv[g0 + j] = rsqrtf(1.0f + (float)(nstart[j + 1] - nstart[j]));

    // pass 2: place ONLY edges whose dst is MLP-needed
    for (int j = t; j < nb; j += 256) cnt[j] = 0;
    __syncthreads();
    for (int i = t; i < cntb; i += 256) {
        int p = pairs[sb + i];
        int local = p >> 17;
        if (nflag[local]) {
            int r = atomicAdd(&cnt[local], 1);
            bucket[lo + nstart[local] + r] = p & SRCMASK;
        }
    }
}

// ---------------- fused kernels (block-range dispatch) ----------------------
__global__ __launch_bounds__(256) void fusedA_kernel(const float* __restrict__ x,
                                                     const float* __restrict__ W,
                                                     unsigned short* __restrict__ hbf,
                                                     const void* __restrict__ ei,
                                                     int* __restrict__ coarse_cursor,
                                                     int* __restrict__ pairs, int E,
                                                     const void* __restrict__ idx,
                                                     unsigned char* __restrict__ flags,
                                                     int nIdx, int npart) {
    __shared__ __align__(16) char smem[FH * WP * 2];
    const int b = blockIdx.x;
    if (b < GA)              gemm_role(x, W, hbf, b, smem);
    else if (b < GA + npart) part_role(ei, coarse_cursor, pairs, E, b - GA, smem);
    else                     mark_role(idx, flags, nIdx, b - GA - npart);
}

__global__ __launch_bounds__(256) void fusedB_kernel(const float* __restrict__ x,
                                                     const float* __restrict__ W,
                                                     unsigned short* __restrict__ hbf,
                                                     const int* __restrict__ pairs,
                                                     const int* __restrict__ coarse_cursor,
                                                     int* __restrict__ cursor,
                                                     float* __restrict__ dinv,
                                                     int* __restrict__ bucket,
                                                     const unsigned char* __restrict__ flags) {
    __shared__ __align__(16) char smem[FH * WP * 2];
    const int b = blockIdx.x;
    if (b < GB) gemm_role(x, W, hbf, GA + b, smem);
    else        place_role(pairs, coarse_cursor, cursor, dinv, bucket, flags, b - GB, smem);
}

// ---------------- fused gather+MLP: one wave per pair -----------------------
// lanes 0-31: endpoint i0 (4 edge slots x 8 col-chunks); lanes 32-63: i1.
__global__ __launch_bounds__(256) void gmlp_kernel(const unsigned short* __restrict__ hbf,
                                                   const float* __restrict__ dinv,
                                                   const int* __restrict__ cursor,
                                                   const int* __restrict__ bucket,
                                                   const float* __restrict__ b_conv,
                                                   const void* __restrict__ idx,
                                                   const float* __restrict__ W1,
                                                   const float* __restrict__ b1,
                                                   const float* __restrict__ W2,
                                                   const float* __restrict__ b2,
                                                   float* __restrict__ out,
                                                   int B) {
    const int pair = blockIdx.x * 4 + (threadIdx.x >> 6);
    const int lane = threadIdx.x & 63;
    const int sub  = lane & 7;      // col chunk (8 bf16)
    const int slot = (lane >> 3) & 3;  // edge slot within endpoint
    const int half = lane >> 5;     // 0: i0, 1: i1
    const int is64 = is64_ballot(idx);

    // MLP weights (every lane)
    float w1a[16], w1b[16], b1r[16], w2r[16];
#pragma unroll
    for (int o = 0; o < 16; ++o) {
        w1a[o] = W1[lane * 16 + o];
        w1b[o] = W1[(64 + lane) * 16 + o];
        b1r[o] = b1[o];
        w2r[o] = W2[o];
    }
    const float b2v = b2[0];
    if (pair >= B) return;

    const long long i0 = load_idx(idx, 2LL * pair, is64);
    const long long i1 = load_idx(idx, 2LL * pair + 1, is64);
    const long long node = half ? i1 : i0;

    const int base = cursor[node];
    const int end  = cursor[node + 1];
    const float dd = dinv[node];

    float acc[8] = {0,0,0,0,0,0,0,0};
    for (int k = base + slot; k < end; k += 4) {
        int s = bucket[k];
        float nrm = dinv[s] * dd;
        short8x hv = *(const short8x*)(hbf + (long long)s * FH + sub * 8);
#pragma unroll
        for (int j = 0; j < 8; ++j)
            acc[j] += bf2f((unsigned short)hv[j]) * nrm;
    }
    // reduce over the 4 slots within each 32-lane half (xor 8, 16)
#pragma unroll
    for (int m = 8; m <= 16; m <<= 1) {
#pragma unroll
        for (int j = 0; j < 8; ++j) acc[j] += __shfl_xor(acc[j], m);
    }
    // self-loop + bias + leaky (every lane of the half now holds its chunk sum)
    short8x hs = *(const short8x*)(hbf + (long long)node * FH + sub * 8);
    float val[8];
#pragma unroll
    for (int j = 0; j < 8; ++j) {
        float v = acc[j] + bf2f((unsigned short)hs[j]) * dd * dd + b_conv[sub * 8 + j];
        val[j] = v >= 0.f ? v : NEG * v;
    }

    // redistribute: lane l <- cat[l] (from half0 lane l>>3) and cat[64+l] (half1)
    float a = 0.f, b = 0.f;
#pragma unroll
    for (int q = 0; q < 8; ++q) {
        float va = __shfl(val[q], lane >> 3);
        float vb = __shfl(val[q], 32 + (lane >> 3));
        if ((lane & 7) == q) { a = va; b = vb; }
    }

    // MLP: z = leaky(cat @ W1 + b1); out = sigmoid(z @ W2 + b2)
    float acc16[16];
#pragma unroll
    for (int o = 0; o < 16; ++o) acc16[o] = a * w1a[o] + b * w1b[o];
#pragma unroll
    for (int m = 1; m < 64; m <<= 1) {
#pragma unroll
        for (int o = 0; o < 16; ++o) acc16[o] += __shfl_xor(acc16[o], m, 64);
    }
    if (lane == 0) {
        float s = b2v;
#pragma unroll
        for (int o = 0; o < 16; ++o) {
            float z = acc16[o] + b1r[o];
            z = z >= 0.f ? z : NEG * z;
            s += z * w2r[o];
        }
        out[pair] = 1.f / (1.f + expf(-s));
    }
}

// ------------------------- fallback (round-1) path --------------------------

__global__ void detect_kernel(const int* __restrict__ ei32, int* __restrict__ flag) {
    if (blockIdx.x == 0 && threadIdx.x == 0) {
        int ok = 1;
        for (int k = 0; k < 64; ++k)
            if (ei32[2 * k + 1] != 0) { ok = 0; break; }
        *flag = ok;
    }
}

__global__ __launch_bounds__(256) void gemm_kernel(const float* __restrict__ x,
                                                   const float* __restrict__ W,
                                                   float* __restrict__ h) {
    __shared__ float xs[4 * FIN];
    __shared__ float part[4][4][FH];

    const int col = threadIdx.x & 63;
    const int kseg = threadIdx.x >> 6;

    float wreg[64];
#pragma unroll
    for (int kk = 0; kk < 64; ++kk)
        wreg[kk] = W[(kseg * 64 + kk) * FH + col];

    for (int row0 = blockIdx.x * 4; row0 < NN; row0 += gridDim.x * 4) {
        const float4* xv = (const float4*)(x + (long long)row0 * FIN);
        ((float4*)xs)[threadIdx.x] = xv[threadIdx.x];
        __syncthreads();

        float acc[4] = {0.f, 0.f, 0.f, 0.f};
#pragma unroll
        for (int kk = 0; kk < 64; ++kk) {
            const float w = wreg[kk];
            const int k = kseg * 64 + kk;
#pragma unroll
            for (int r = 0; r < 4; ++r)
                acc[r] += xs[r * FIN + k] * w;
        }
#pragma unroll
        for (int r = 0; r < 4; ++r) part[r][kseg][col] = acc[r];
        __syncthreads();

        const int row = threadIdx.x >> 6;
        float s = part[row][0][col] + part[row][1][col] + part[row][2][col] + part[row][3][col];
        h[(long long)(row0 + row) * FH + col] = s;
        __syncthreads();
    }
}

__global__ __launch_bounds__(256) void init_kernel(float* __restrict__ ne,
                                                   float* __restrict__ deg,
                                                   const float* __restrict__ b_conv) {
    int idx = blockIdx.x * 256 + threadIdx.x;
    if (idx < NN * FH) ne[idx] = b_conv[idx & (FH - 1)];
    if (idx < NN) deg[idx] = 1.0f;
}

__global__ __launch_bounds__(256) void deg_kernel(const void* __restrict__ ei,
                                                  float* __restrict__ deg,
                                                  int E, const int* __restrict__ flag) {
    int e = blockIdx.x * 256 + threadIdx.x;
    if (e >= E) return;
    long long d = load_idx(ei, (long long)E + e, *flag);
    atomicAdd(&deg[d], 1.0f);
}

__global__ __launch_bounds__(256) void rsqrt_kernel(float* __restrict__ deg) {
    int i = blockIdx.x * 256 + threadIdx.x;
    if (i < NN) deg[i] = rsqrtf(deg[i]);
}

__global__ __launch_bounds__(256) void selfloop_kernel(const float* __restrict__ h,
                                                       const float* __restrict__ dinv,
                                                       float* __restrict__ ne) {
    int idx = blockIdx.x * 256 + threadIdx.x;
    if (idx >= NN * FH) return;
    int i = idx >> 6;
    float di = dinv[i];
    ne[idx] += h[idx] * di * di;
}

__global__ __launch_bounds__(256) void edge_agg_kernel(const void* __restrict__ ei,
                                                       const float* __restrict__ dinv,
                                                       const float* __restrict__ h,
                                                       float* __restrict__ ne,
                                                       int E, const int* __restrict__ flag) {
    long long t = (long long)blockIdx.x * 256 + threadIdx.x;
    long long e = t >> 4;
    int sub = (int)(t & 15);
    if (e >= E) return;
    int is64 = *flag;
    long long s = load_idx(ei, e, is64);
    long long d = load_idx(ei, (long long)E + e, is64);
    float nrm = dinv[s] * dinv[d];
    float4 hv = *(const float4*)(h + s * FH + sub * 4);
    float* np_ = ne + d * FH + sub * 4;
    atomicAdd(np_ + 0, hv.x * nrm);
    atomicAdd(np_ + 1, hv.y * nrm);
    atomicAdd(np_ + 2, hv.z * nrm);
    atomicAdd(np_ + 3, hv.w * nrm);
}

__global__ __launch_bounds__(256) void mlp_fb_kernel(const float* __restrict__ ne,
                                                     const void* __restrict__ idx,
                                                     const float* __restrict__ W1,
                                                     const float* __restrict__ b1,
                                                     const float* __restrict__ W2,
                                                     const float* __restrict__ b2,
                                                     float* __restrict__ out,
                                                     int B, const int* __restrict__ flag) {
    const int lane = threadIdx.x & 63;
    const int wid = threadIdx.x >> 6;

    float w1a[16], w1b[16], b1r[16], w2r[16];
#pragma unroll
    for (int o = 0; o < 16; ++o) {
        w1a[o] = W1[lane * 16 + o];
        w1b[o] = W1[(64 + lane) * 16 + o];
        b1r[o] = b1[o];
        w2r[o] = W2[o];
    }
    const float b2v = b2[0];
    const int is64 = *flag;

    for (int pair = blockIdx.x * 4 + wid; pair < B; pair += gridDim.x * 4) {
        long long i0 = load_idx(idx, 2LL * pair, is64);
        long long i1 = load_idx(idx, 2LL * pair + 1, is64);
        float a = ne[i0 * FH + lane];
        float b = ne[i1 * FH + lane];
        a = a >= 0.f ? a : NEG * a;
        b = b >= 0.f ? b : NEG * b;

        float acc[16];
#pragma unroll
        for (int o = 0; o < 16; ++o) acc[o] = a * w1a[o] + b * w1b[o];
#pragma unroll
        for (int m = 1; m < 64; m <<= 1) {
#pragma unroll
            for (int o = 0; o < 16; ++o) acc[o] += __shfl_xor(acc[o], m, 64);
        }
        if (lane == 0) {
            float s = b2v;
#pragma unroll
            for (int o = 0; o < 16; ++o) {
                float z = acc[o] + b1r[o];
                z = z >= 0.f ? z : NEG * z;
                s += z * w2r[o];
            }
            out[pair] = 1.f / (1.f + expf(-s));
        }
    }
}

extern "C" void kernel_launch(void* const* d_in, const int* in_sizes, int n_in,
                              void* d_out, int out_size, void* d_ws, size_t ws_size,
                              hipStream_t stream) {
    const float* x      = (const float*)d_in[0];
    const void*  ei     = d_in[1];
    const void*  index  = d_in[2];
    const float* W_conv = (const float*)d_in[3];
    const float* b_conv = (const float*)d_in[4];
    const float* W1     = (const float*)d_in[5];
    const float* b1     = (const float*)d_in[6];
    const float* W2     = (const float*)d_in[7];
    const float* b2     = (const float*)d_in[8];
    float* out = (float*)d_out;

    const int E = in_sizes[1] / 2;   // 1.6M
    const int B = in_sizes[2] / 2;   // 16384

    const size_t need_new = (size_t)NN * FH * 2
                          + ((size_t)NN * FH + NN + (NN + 1) + (size_t)E + NBUCK) * 4
                          + NN;      // flags

    if (ws_size >= need_new && (size_t)NBUCK * SLAB <= (size_t)NN * FH) {
        unsigned short* hbf = (unsigned short*)d_ws;
        float* scratch  = (float*)(hbf + (long long)NN * FH);
        float* dinv     = scratch + (long long)NN * FH;
        int*   cursor   = (int*)(dinv + NN);          // NN+1 entries
        int*   bucket   = cursor + (NN + 1);
        int*   coarse_cursor = bucket + E;            // NBUCK
        unsigned char* flags = (unsigned char*)(coarse_cursor + NBUCK);
        int*   pairs    = (int*)scratch;              // slab array

        const int npart = (E + P1_CH - 1) / P1_CH;
        const int nmark = (2 * B + 255) / 256;

        prep_kernel<<<1 + (NN + 255) / 256, 256, 0, stream>>>(coarse_cursor, flags);
        fusedA_kernel<<<GA + npart + nmark, 256, 0, stream>>>(x, W_conv, hbf, ei,
                                                              coarse_cursor, pairs, E,
                                                              index, flags, 2 * B, npart);
        fusedB_kernel<<<GB + NBUCK, 256, 0, stream>>>(x, W_conv, hbf, pairs, coarse_cursor,
                                                      cursor, dinv, bucket, flags);
        gmlp_kernel<<<(B + 3) / 4, 256, 0, stream>>>(hbf, dinv, cursor, bucket, b_conv,
                                                     index, W1, b1, W2, b2, out, B);
    } else {
        // fallback: round-1 atomic scatter (fp32)
        float* h   = (float*)d_ws;
        float* ne  = h + (long long)NN * FH;
        float* deg = ne + (long long)NN * FH;
        int* flag  = (int*)(deg + NN);

        detect_kernel<<<1, 64, 0, stream>>>((const int*)ei, flag);
        init_kernel<<<(NN * FH + 255) / 256, 256, 0, stream>>>(ne, deg, b_conv);
        gemm_kernel<<<2048, 256, 0, stream>>>(x, W_conv, h);
        deg_kernel<<<(E + 255) / 256, 256, 0, stream>>>(ei, deg, E, flag);
        rsqrt_kernel<<<(NN + 255) / 256, 256, 0, stream>>>(deg);
        selfloop_kernel<<<(NN * FH + 255) / 256, 256, 0, stream>>>(h, deg, ne);
        edge_agg_kernel<<<(int)(((long long)E * 16 + 255) / 256), 256, 0, stream>>>(ei, deg, h, ne, E, flag);
        mlp_fb_kernel<<<512, 256, 0, stream>>>(ne, index, W1, b1, W2, b2, out, B, flag);
    }
}